// Round 1
// baseline (291.472 us; speedup 1.0000x reference)
//
#include <hip/hip_runtime.h>

// SmoothL1 word loss (packed mean) + sentence loss (per-batch time-means).
// preds/targets: [B=32, T=2048, D=512] fp32; decode_lengths: [32] int32; out: 1 fp32.
// BETA = 1.0 -> sl1(d) = |d|<1 ? 0.5 d^2 : |d| - 0.5
//
// V2: atomic-free pass1. Each (b,chunk) block writes partial column sums to
// part[b][chunk][:] and a word-loss partial to wpart[b*64+chunk]; pass2 folds
// only valid chunks (c*32 < len), so no workspace zero-init is needed at all
// (poisoned ws bytes are never read). Removes ~1M device-scope atomics + the
// memset node + its serialization against pass1.

#define BATCH 32
#define TLEN  2048
#define DDIM  512
#define ROWS  32                    // rows per (b,chunk) block
#define NCHUNK (TLEN / ROWS)        // 64
#define P1_THREADS 128              // 128 threads x float4 = 512 columns

__device__ __forceinline__ float sl1(float d) {
    float ad = fabsf(d);
    return ad < 1.0f ? 0.5f * d * d : ad - 0.5f;
}

// Pass 1: per-(b,chunk) partial column sums of preds/targets over valid t,
// plus per-chunk word-loss partial. No atomics, no zero-init dependency.
__global__ __launch_bounds__(P1_THREADS)
void pass1(const float* __restrict__ preds, const float* __restrict__ targs,
           const int* __restrict__ lens,
           float* __restrict__ partp,   // [B][NCHUNK][D]
           float* __restrict__ partt,   // [B][NCHUNK][D]
           float* __restrict__ wpart)   // [B*NCHUNK]
{
    const int b     = blockIdx.x;
    const int chunk = blockIdx.y;
    const int len   = lens[b];
    const int t0    = chunk * ROWS;
    if (t0 >= len) return;               // invalid chunk: pass2 won't read it
    const int t1 = min(t0 + ROWS, len);

    const float4* __restrict__ p4 = (const float4*)(preds + (size_t)b * TLEN * DDIM);
    const float4* __restrict__ q4 = (const float4*)(targs + (size_t)b * TLEN * DDIM);
    const int lane4 = threadIdx.x;       // float4 index within a row

    float4 sp = make_float4(0.f, 0.f, 0.f, 0.f);
    float4 st = make_float4(0.f, 0.f, 0.f, 0.f);
    float  w  = 0.f;

    for (int t = t0; t < t1; ++t) {
        float4 p = p4[(size_t)t * (DDIM / 4) + lane4];
        float4 q = q4[(size_t)t * (DDIM / 4) + lane4];
        sp.x += p.x; sp.y += p.y; sp.z += p.z; sp.w += p.w;
        st.x += q.x; st.y += q.y; st.z += q.z; st.w += q.w;
        w += sl1(p.x - q.x) + sl1(p.y - q.y) + sl1(p.z - q.z) + sl1(p.w - q.w);
    }

    // Plain coalesced stores of this chunk's partials (no contention).
    float4* op = (float4*)(partp + ((size_t)b * NCHUNK + chunk) * DDIM);
    float4* ot = (float4*)(partt + ((size_t)b * NCHUNK + chunk) * DDIM);
    op[lane4] = sp;
    ot[lane4] = st;

    // Word-loss partial: wave reduce (wave=64), combine 2 waves, one store.
    #pragma unroll
    for (int off = 32; off; off >>= 1) w += __shfl_down(w, off);
    __shared__ float ws[P1_THREADS / 64];
    if ((threadIdx.x & 63) == 0) ws[threadIdx.x >> 6] = w;
    __syncthreads();
    if (threadIdx.x == 0) wpart[b * NCHUNK + chunk] = ws[0] + ws[1];
}

// Pass 2: fold valid chunk partials -> sentence loss; fold word partials;
// combine and write the scalar. Single block, 1024 threads (16 waves).
__global__ __launch_bounds__(1024)
void pass2(const float* __restrict__ partp, const float* __restrict__ partt,
           const int* __restrict__ lens, const float* __restrict__ wpart,
           float* __restrict__ out)
{
    const int tid = threadIdx.x;

    // Sentence: 32*128 float4 cells; each thread owns 4 cells; inner loop over
    // valid chunks only. Reads are coalesced across tid (d4 varies fastest).
    float s = 0.f;
    for (int i = tid; i < BATCH * (DDIM / 4); i += 1024) {
        const int b   = i >> 7;          // i / (DDIM/4)
        const int d4  = i & 127;
        const int len = lens[b];
        const int nch = (len + ROWS - 1) / ROWS;
        const float4* pp = (const float4*)(partp + (size_t)b * NCHUNK * DDIM) + d4;
        const float4* tt = (const float4*)(partt + (size_t)b * NCHUNK * DDIM) + d4;
        float4 cp = make_float4(0.f, 0.f, 0.f, 0.f);
        float4 ct = make_float4(0.f, 0.f, 0.f, 0.f);
        for (int c = 0; c < nch; ++c) {
            float4 a  = pp[(size_t)c * (DDIM / 4)];
            float4 bb = tt[(size_t)c * (DDIM / 4)];
            cp.x += a.x; cp.y += a.y; cp.z += a.z; cp.w += a.w;
            ct.x += bb.x; ct.y += bb.y; ct.z += bb.z; ct.w += bb.w;
        }
        const float invL = 1.f / (float)len;
        s += sl1((cp.x - ct.x) * invL) + sl1((cp.y - ct.y) * invL)
           + sl1((cp.z - ct.z) * invL) + sl1((cp.w - ct.w) * invL);
    }

    // Word partials: only valid chunks were written; skip the rest.
    float wsum = 0.f;
    for (int i = tid; i < BATCH * NCHUNK; i += 1024) {
        const int b = i >> 6;
        const int c = i & (NCHUNK - 1);
        if (c * ROWS < lens[b]) wsum += wpart[i];
    }

    // Block reduction of both sums.
    #pragma unroll
    for (int off = 32; off; off >>= 1) {
        s    += __shfl_down(s, off);
        wsum += __shfl_down(wsum, off);
    }
    __shared__ float rs[16], rw[16];
    if ((tid & 63) == 0) { rs[tid >> 6] = s; rw[tid >> 6] = wsum; }
    __syncthreads();
    if (tid == 0) {
        float sent = 0.f, word = 0.f;
        #pragma unroll
        for (int i = 0; i < 16; ++i) { sent += rs[i]; word += rw[i]; }
        float nvalid = 0.f;
        for (int b = 0; b < BATCH; ++b) nvalid += (float)lens[b];
        out[0] = word / (nvalid * (float)DDIM)
               + sent / ((float)DDIM * (float)BATCH);
    }
}

extern "C" void kernel_launch(void* const* d_in, const int* in_sizes, int n_in,
                              void* d_out, int out_size, void* d_ws, size_t ws_size,
                              hipStream_t stream) {
    const float* preds = (const float*)d_in[0];
    const float* targs = (const float*)d_in[1];
    const int*   lens  = (const int*)d_in[2];
    float* out = (float*)d_out;

    // Workspace layout (fp32): partp [B*NCHUNK*D], partt [B*NCHUNK*D],
    // wpart [B*NCHUNK]. ~8 MB total. NO zero-init required: pass2 reads only
    // chunks with c*ROWS < len, all of which pass1 wrote this launch.
    float* partp = (float*)d_ws;
    float* partt = partp + (size_t)BATCH * NCHUNK * DDIM;
    float* wpart = partt + (size_t)BATCH * NCHUNK * DDIM;

    dim3 grid1(BATCH, NCHUNK);
    pass1<<<grid1, P1_THREADS, 0, stream>>>(preds, targs, lens, partp, partt, wpart);
    pass2<<<1, 1024, 0, stream>>>(partp, partt, lens, wpart, out);
}

// Round 2
// 262.196 us; speedup vs baseline: 1.1117x; 1.1117x over previous
//
#include <hip/hip_runtime.h>

// SmoothL1 word loss (packed mean) + sentence loss (per-batch time-means).
// preds/targets: [B=32, T=2048, D=512] fp32; decode_lengths: [32] int32; out: 1 fp32.
// BETA = 1.0 -> sl1(d) = |d|<1 ? 0.5 d^2 : |d| - 0.5
//
// V3: atomic-free pass1 (unchanged from V2) + GRID-PARALLEL fold.
// V2's regression: single-block pass2 pulled ~8 MB of partials through one CU
// (~28 us). Now pass2 runs 32 blocks (one per batch b), each folding its own
// ~128-256 KB of partials in parallel, writing per-b sentence/word sums;
// pass3 (one wave) combines 32+32 scalars. Still no workspace zero-init:
// only chunks with c*ROWS < len are ever read, all written this launch.

#define BATCH 32
#define TLEN  2048
#define DDIM  512
#define ROWS  32                    // rows per (b,chunk) pass1 block
#define NCHUNK (TLEN / ROWS)        // 64
#define P1_THREADS 128              // 128 threads x float4 = 512 columns

__device__ __forceinline__ float sl1(float d) {
    float ad = fabsf(d);
    return ad < 1.0f ? 0.5f * d * d : ad - 0.5f;
}

// Pass 1: per-(b,chunk) partial column sums of preds/targets over valid t,
// plus per-chunk word-loss partial. No atomics, no zero-init dependency.
__global__ __launch_bounds__(P1_THREADS)
void pass1(const float* __restrict__ preds, const float* __restrict__ targs,
           const int* __restrict__ lens,
           float* __restrict__ partp,   // [B][NCHUNK][D]
           float* __restrict__ partt,   // [B][NCHUNK][D]
           float* __restrict__ wpart)   // [B*NCHUNK]
{
    const int b     = blockIdx.x;
    const int chunk = blockIdx.y;
    const int len   = lens[b];
    const int t0    = chunk * ROWS;
    if (t0 >= len) return;               // invalid chunk: pass2 won't read it
    const int t1 = min(t0 + ROWS, len);

    const float4* __restrict__ p4 = (const float4*)(preds + (size_t)b * TLEN * DDIM);
    const float4* __restrict__ q4 = (const float4*)(targs + (size_t)b * TLEN * DDIM);
    const int lane4 = threadIdx.x;       // float4 index within a row

    float4 sp = make_float4(0.f, 0.f, 0.f, 0.f);
    float4 st = make_float4(0.f, 0.f, 0.f, 0.f);
    float  w  = 0.f;

    for (int t = t0; t < t1; ++t) {
        float4 p = p4[(size_t)t * (DDIM / 4) + lane4];
        float4 q = q4[(size_t)t * (DDIM / 4) + lane4];
        sp.x += p.x; sp.y += p.y; sp.z += p.z; sp.w += p.w;
        st.x += q.x; st.y += q.y; st.z += q.z; st.w += q.w;
        w += sl1(p.x - q.x) + sl1(p.y - q.y) + sl1(p.z - q.z) + sl1(p.w - q.w);
    }

    // Plain coalesced stores of this chunk's partials (no contention).
    float4* op = (float4*)(partp + ((size_t)b * NCHUNK + chunk) * DDIM);
    float4* ot = (float4*)(partt + ((size_t)b * NCHUNK + chunk) * DDIM);
    op[lane4] = sp;
    ot[lane4] = st;

    // Word-loss partial: wave reduce (wave=64), combine 2 waves, one store.
    #pragma unroll
    for (int off = 32; off; off >>= 1) w += __shfl_down(w, off);
    __shared__ float ws[P1_THREADS / 64];
    if ((threadIdx.x & 63) == 0) ws[threadIdx.x >> 6] = w;
    __syncthreads();
    if (threadIdx.x == 0) wpart[b * NCHUNK + chunk] = ws[0] + ws[1];
}

// Pass 2: one block per batch element b. Fold b's valid chunk partials into
// per-b sentence sum (sum_d sl1(mean diff)) and per-b word sum. 128 threads:
// each owns one float4 column group; chunk-partial reads are coalesced.
__global__ __launch_bounds__(128)
void pass2(const float* __restrict__ partp, const float* __restrict__ partt,
           const int* __restrict__ lens, const float* __restrict__ wpart,
           float* __restrict__ sentb,   // [B]
           float* __restrict__ wordb)   // [B]
{
    const int b   = blockIdx.x;
    const int tid = threadIdx.x;         // 0..127 = float4 column group
    const int len = lens[b];
    const int nch = (len + ROWS - 1) / ROWS;

    const float4* pp = (const float4*)(partp + (size_t)b * NCHUNK * DDIM) + tid;
    const float4* tt = (const float4*)(partt + (size_t)b * NCHUNK * DDIM) + tid;
    float4 cp = make_float4(0.f, 0.f, 0.f, 0.f);
    float4 ct = make_float4(0.f, 0.f, 0.f, 0.f);
    for (int c = 0; c < nch; ++c) {
        float4 a = pp[(size_t)c * (DDIM / 4)];
        float4 q = tt[(size_t)c * (DDIM / 4)];
        cp.x += a.x; cp.y += a.y; cp.z += a.z; cp.w += a.w;
        ct.x += q.x; ct.y += q.y; ct.z += q.z; ct.w += q.w;
    }
    const float invL = 1.f / (float)len;
    float s = sl1((cp.x - ct.x) * invL) + sl1((cp.y - ct.y) * invL)
            + sl1((cp.z - ct.z) * invL) + sl1((cp.w - ct.w) * invL);

    // Word partials for this b (only valid chunks were written).
    float w = 0.f;
    for (int c = tid; c < nch; c += 128) w += wpart[b * NCHUNK + c];

    // Reduce s and w across 128 threads (2 waves).
    #pragma unroll
    for (int off = 32; off; off >>= 1) {
        s += __shfl_down(s, off);
        w += __shfl_down(w, off);
    }
    __shared__ float rs[2], rw[2];
    if ((tid & 63) == 0) { rs[tid >> 6] = s; rw[tid >> 6] = w; }
    __syncthreads();
    if (tid == 0) { sentb[b] = rs[0] + rs[1]; wordb[b] = rw[0] + rw[1]; }
}

// Pass 3: one wave combines the 32 per-b sums into the output scalar.
__global__ __launch_bounds__(64)
void pass3(const float* __restrict__ sentb, const float* __restrict__ wordb,
           const int* __restrict__ lens, float* __restrict__ out)
{
    const int tid = threadIdx.x;         // 0..63
    float s = 0.f, w = 0.f, n = 0.f;
    if (tid < BATCH) {
        s = sentb[tid];
        w = wordb[tid];
        n = (float)lens[tid];
    }
    #pragma unroll
    for (int off = 32; off; off >>= 1) {
        s += __shfl_down(s, off);
        w += __shfl_down(w, off);
        n += __shfl_down(n, off);
    }
    if (tid == 0)
        out[0] = w / (n * (float)DDIM) + s / ((float)DDIM * (float)BATCH);
}

extern "C" void kernel_launch(void* const* d_in, const int* in_sizes, int n_in,
                              void* d_out, int out_size, void* d_ws, size_t ws_size,
                              hipStream_t stream) {
    const float* preds = (const float*)d_in[0];
    const float* targs = (const float*)d_in[1];
    const int*   lens  = (const int*)d_in[2];
    float* out = (float*)d_out;

    // Workspace (fp32): partp [B*NCHUNK*D], partt [B*NCHUNK*D], wpart [B*NCHUNK],
    // sentb [B], wordb [B]. ~8 MB. No zero-init required: every word pass2/3
    // read is written earlier in this launch (valid-chunk indexing).
    float* partp = (float*)d_ws;
    float* partt = partp + (size_t)BATCH * NCHUNK * DDIM;
    float* wpart = partt + (size_t)BATCH * NCHUNK * DDIM;
    float* sentb = wpart + BATCH * NCHUNK;
    float* wordb = sentb + BATCH;

    dim3 grid1(BATCH, NCHUNK);
    pass1<<<grid1, P1_THREADS, 0, stream>>>(preds, targs, lens, partp, partt, wpart);
    pass2<<<BATCH, 128, 0, stream>>>(partp, partt, lens, wpart, sentb, wordb);
    pass3<<<1, 64, 0, stream>>>(sentb, wordb, lens, out);
}